// Round 1
// 602.844 us; speedup vs baseline: 1.0211x; 1.0211x over previous
//
#include <hip/hip_runtime.h>
#include <cstddef>
#include <cstdint>

#define B 256
#define N 2048
#define DH 128
#define DG 256
#define HID 256
#define SPLITS 8
#define CHUNK (N / SPLITS)            // 256 rows per block
#define ROWS_PER_ITER 32              // 4 waves * 8 rows
#define KITER (CHUNK / ROWS_PER_ITER) // 8
#define SCALE 0.08838834764831845f
#define LN_EPS 1e-5f
#define TAN_NORM_MAX 6.2f  // artanh(1-1e-5)=6.103; safe upper bound

// ---------- helpers ----------

__device__ __forceinline__ float artanh_clip(float a) {
  a = fminf(a, 1.0f - 1e-5f);
  return 0.5f * __logf((1.0f + a) / (1.0f - a));
}

__device__ __forceinline__ float logmap_scale(float n2) {
  float nc = fmaxf(sqrtf(n2), 1e-7f);
  return artanh_clip(nc) / nc;
}

// allreduce-sum across each 16-lane DPP row using ROW_ROR (pure VALU, no LDS pipe)
__device__ __forceinline__ float row16_sum(float x) {
  x += __int_as_float(__builtin_amdgcn_update_dpp(0, __float_as_int(x), 0x128, 0xF, 0xF, true)); // ror:8
  x += __int_as_float(__builtin_amdgcn_update_dpp(0, __float_as_int(x), 0x124, 0xF, 0xF, true)); // ror:4
  x += __int_as_float(__builtin_amdgcn_update_dpp(0, __float_as_int(x), 0x122, 0xF, 0xF, true)); // ror:2
  x += __int_as_float(__builtin_amdgcn_update_dpp(0, __float_as_int(x), 0x121, 0xF, 0xF, true)); // ror:1
  return x;
}

__device__ __forceinline__ float dotN(const float* __restrict__ wrow,
                                      const float* __restrict__ x, int n4) {
  const float4* a = (const float4*)wrow;
  const float4* bx = (const float4*)x;
  float s = 0.f;
  for (int j = 0; j < n4; ++j) {
    float4 u = a[j], v = bx[j];
    s += u.x * v.x + u.y * v.y + u.z * v.z + u.w * v.w;
  }
  return s;
}

// block reduction over 128 threads (2 waves)
__device__ __forceinline__ float blockSum128(float v, float* s_red) {
#pragma unroll
  for (int msk = 1; msk < 64; msk <<= 1) v += __shfl_xor(v, msk);
  if ((threadIdx.x & 63) == 0) s_red[threadIdx.x >> 6] = v;
  __syncthreads();
  float r = s_red[0] + s_red[1];
  __syncthreads();
  return r;
}

// merge SPLITS per-block partials (shared fixed max Mb => plain sums)
__device__ __forceinline__ float combine_partials(const float* __restrict__ partials,
                                                  int b, int tid) {
  const float* pb = partials + (size_t)b * SPLITS * (DH + 2);
  float L = 0.f, a = 0.f;
#pragma unroll
  for (int s = 0; s < SPLITS; ++s) {
    L += pb[s * (DH + 2) + DH];
    a += pb[s * (DH + 2) + tid];
  }
  return a / L;
}

// ---------- kernel 0: pooled-attention query ----------

__global__ void setup_pool_query(const float* __restrict__ rho,
                                 const float* __restrict__ seed_g_w,
                                 const float* __restrict__ seed_g_b,
                                 const float* __restrict__ pool_wq_w,
                                 const float* __restrict__ pool_wk_w,
                                 float* __restrict__ q_seed,
                                 float* __restrict__ qvec,
                                 float* __restrict__ mb) {
  const int b = blockIdx.x, tid = threadIdx.x;
  __shared__ __align__(16) float s_rho[DG];
  __shared__ __align__(16) float s_qs[DH];
  __shared__ __align__(16) float s_qk[DH];
  __shared__ float s_red[2];
  s_rho[tid] = rho[b * DG + tid];
  s_rho[tid + DH] = rho[b * DG + tid + DH];
  __syncthreads();
  float qs = seed_g_b[tid] + dotN(seed_g_w + (size_t)tid * DG, s_rho, DG / 4);
  q_seed[b * DH + tid] = qs;
  s_qs[tid] = qs;
  __syncthreads();
  float qk = dotN(pool_wq_w + (size_t)tid * DH, s_qs, DH / 4);
  s_qk[tid] = qk;
  __syncthreads();
  float qp = 0.f;
  for (int i = 0; i < DH; ++i) qp += pool_wk_w[i * DH + tid] * s_qk[i];
  qvec[b * DH + tid] = qp;
  float qn2 = blockSum128(qp * qp, s_red);
  if (tid == 0) mb[b] = SCALE * TAN_NORM_MAX * sqrtf(qn2);
}

// ---------- attention pass ----------
// Fixed-bound softmax: Mb >= max score, so exp(s-Mb) never overflows; plain sums.
// Layout: 16 lanes per row, 8 floats per lane (two float4 halves of the 128-float row).
// Each wave handles 8 rows per k-iter (two 4-row groups), one-iter-ahead prefetch.
// Row reduction = 4 fused DPP row_ror adds (VALU only, no ds_bpermute, no LDS pipe).
// LOADTS=0 (pass 1): compute logmap scale ts per row, store to ts_buf.
// LOADTS=1 (passes 2,3): load precomputed ts; no n2 reduce, no sqrt/log/rcp chain.

template <int LOADTS>
__global__ __launch_bounds__(256, 6) void attn_pass(const float* __restrict__ demo,
                                                    const float* __restrict__ qvec,
                                                    const float* __restrict__ mb,
                                                    float* __restrict__ partials,
                                                    float* __restrict__ ts_buf) {
  const int blk = blockIdx.x;
  const int b = blk >> 3;       // SPLITS == 8
  const int s = blk & 7;
  const int tid = threadIdx.x;
  const int w = tid >> 6;       // wave id 0..3
  const int lane = tid & 63;
  const int g = lane >> 4;      // row-in-group 0..3
  const int il = lane & 15;     // slot within 16-lane row group

  // query slice for this lane: floats [4il..4il+3] and [64+4il..64+4il+3]
  const float4 qv0 = *(const float4*)(qvec + b * DH + il * 4);
  const float4 qv1 = *(const float4*)(qvec + b * DH + 64 + il * 4);
  const float Mb = mb[b];

  // absolute row index of this lane's group-A row at k=0
  const size_t row0 = (size_t)b * N + (size_t)s * CHUNK + (size_t)(w * 8);
  const float* p = demo + (row0 + g) * DH + il * 4;
  const size_t rts = row0 + g;

  float lsum = 0.f;
  float4 accL = make_float4(0.f, 0.f, 0.f, 0.f);
  float4 accH = make_float4(0.f, 0.f, 0.f, 0.f);

  float4 xa1 = *(const float4*)(p);
  float4 xa2 = *(const float4*)(p + 64);
  float4 xb1 = *(const float4*)(p + 4 * DH);
  float4 xb2 = *(const float4*)(p + 4 * DH + 64);
  float tsA = 0.f, tsB = 0.f;
  if (LOADTS) { tsA = ts_buf[rts]; tsB = ts_buf[rts + 4]; }

  for (int k = 0; k < KITER; ++k) {
    float4 ca1 = xa1, ca2 = xa2, cb1 = xb1, cb2 = xb2;
    float tA = tsA, tB = tsB;
    if (k + 1 < KITER) {
      const float* pn = p + (size_t)(k + 1) * ROWS_PER_ITER * DH;
      xa1 = *(const float4*)(pn);
      xa2 = *(const float4*)(pn + 64);
      xb1 = *(const float4*)(pn + 4 * DH);
      xb2 = *(const float4*)(pn + 4 * DH + 64);
      if (LOADTS) {
        tsA = ts_buf[rts + (size_t)(k + 1) * ROWS_PER_ITER];
        tsB = ts_buf[rts + (size_t)(k + 1) * ROWS_PER_ITER + 4];
      }
    }
    // group A (rows k*32 + w*8 + g)
    {
      float dd = qv0.x * ca1.x + qv0.y * ca1.y + qv0.z * ca1.z + qv0.w * ca1.w +
                 qv1.x * ca2.x + qv1.y * ca2.y + qv1.z * ca2.z + qv1.w * ca2.w;
      dd = row16_sum(dd);
      float tsv;
      if (LOADTS) {
        tsv = tA;
      } else {
        float n2 = ca1.x * ca1.x + ca1.y * ca1.y + ca1.z * ca1.z + ca1.w * ca1.w +
                   ca2.x * ca2.x + ca2.y * ca2.y + ca2.z * ca2.z + ca2.w * ca2.w;
        n2 = row16_sum(n2);
        tsv = logmap_scale(n2);
        if (il == 0) ts_buf[rts + (size_t)k * ROWS_PER_ITER] = tsv;
      }
      float pw = __expf(dd * tsv * SCALE - Mb);
      lsum += pw;
      float c = pw * tsv;
      accL.x += c * ca1.x; accL.y += c * ca1.y; accL.z += c * ca1.z; accL.w += c * ca1.w;
      accH.x += c * ca2.x; accH.y += c * ca2.y; accH.z += c * ca2.z; accH.w += c * ca2.w;
    }
    // group B (rows k*32 + w*8 + 4 + g)
    {
      float dd = qv0.x * cb1.x + qv0.y * cb1.y + qv0.z * cb1.z + qv0.w * cb1.w +
                 qv1.x * cb2.x + qv1.y * cb2.y + qv1.z * cb2.z + qv1.w * cb2.w;
      dd = row16_sum(dd);
      float tsv;
      if (LOADTS) {
        tsv = tB;
      } else {
        float n2 = cb1.x * cb1.x + cb1.y * cb1.y + cb1.z * cb1.z + cb1.w * cb1.w +
                   cb2.x * cb2.x + cb2.y * cb2.y + cb2.z * cb2.z + cb2.w * cb2.w;
        n2 = row16_sum(n2);
        tsv = logmap_scale(n2);
        if (il == 0) ts_buf[rts + (size_t)k * ROWS_PER_ITER + 4] = tsv;
      }
      float pw = __expf(dd * tsv * SCALE - Mb);
      lsum += pw;
      float c = pw * tsv;
      accL.x += c * cb1.x; accL.y += c * cb1.y; accL.z += c * cb1.z; accL.w += c * cb1.w;
      accH.x += c * cb2.x; accH.y += c * cb2.y; accH.z += c * cb2.z; accH.w += c * cb2.w;
    }
  }

  // fold 4 waves x 4 groups = 16 partial (acc, l) into one
  __shared__ __align__(16) float s_acc[16][DH];
  __shared__ float s_l[16];
  const int slot = (w << 2) | g;
  *(float4*)&s_acc[slot][il * 4] = accL;
  *(float4*)&s_acc[slot][64 + il * 4] = accH;
  if (il == 0) s_l[slot] = lsum;
  __syncthreads();
  if (tid < DH) {
    float a = 0.f;
#pragma unroll
    for (int j = 0; j < 16; ++j) a += s_acc[j][tid];
    float* pp = partials + (size_t)blk * (DH + 2);
    pp[tid] = a;
    if (tid == 0) {
      float L = 0.f;
#pragma unroll
      for (int j = 0; j < 16; ++j) L += s_l[j];
      pp[DH] = L;
    }
  }
}

// ---------- transition after pool pass ----------

__global__ void trans_pool(const float* __restrict__ partials,
                           const float* __restrict__ q_seed,
                           const float* __restrict__ rho,
                           const float* __restrict__ pool_wv_w,
                           const float* __restrict__ seed_d_w,
                           const float* __restrict__ q_u_w,
                           const float* __restrict__ q_g_w,
                           const float* __restrict__ q_g_b,
                           const float* __restrict__ kv_w,
                           const float* __restrict__ ln_g,
                           const float* __restrict__ ln_b,
                           float* __restrict__ u_tan_out,
                           float* __restrict__ qvec_out,
                           float* __restrict__ mb) {
  const int b = blockIdx.x, tid = threadIdx.x;
  __shared__ __align__(16) float s_a[DH];
  __shared__ __align__(16) float s_b[DH];
  __shared__ __align__(16) float s_rho[DG];
  __shared__ float s_red[2];

  float w0 = combine_partials(partials, b, tid);
  s_a[tid] = w0;
  s_rho[tid] = rho[b * DG + tid];
  s_rho[tid + DH] = rho[b * DG + tid + DH];
  __syncthreads();
  float pooled = dotN(pool_wv_w + (size_t)tid * DH, s_a, DH / 4);
  s_b[tid] = pooled;
  __syncthreads();
  float v = q_seed[b * DH + tid] + dotN(seed_d_w + (size_t)tid * DH, s_b, DH / 4);
  // expmap0
  float n2 = blockSum128(v * v, s_red);
  float nc = fmaxf(sqrtf(n2), 1e-7f);
  float u = v * (tanhf(nc) / nc);
  // logmap0
  float nu2 = blockSum128(u * u, s_red);
  float nuc = fmaxf(sqrtf(nu2), 1e-7f);
  float ut = u * (artanh_clip(nuc) / nuc);
  // LayerNorm
  float mu = blockSum128(ut, s_red) * (1.0f / DH);
  float d = ut - mu;
  float var = blockSum128(d * d, s_red) * (1.0f / DH);
  float y = d * rsqrtf(var + LN_EPS) * ln_g[tid] + ln_b[tid];
  u_tan_out[b * DH + tid] = y;
  s_a[tid] = y;
  __syncthreads();
  float q = q_g_b[tid] + dotN(q_u_w + (size_t)tid * DH, s_a, DH / 4) +
            dotN(q_g_w + (size_t)tid * DG, s_rho, DG / 4);
  s_b[tid] = q;
  __syncthreads();
  float qp = 0.f;
  for (int i = 0; i < DH; ++i) qp += kv_w[i * DH + tid] * s_b[i];
  qvec_out[b * DH + tid] = qp;
  float qn2 = blockSum128(qp * qp, s_red);
  if (tid == 0) mb[b] = SCALE * TAN_NORM_MAX * sqrtf(qn2);
}

// ---------- loop-iteration transition ----------

__global__ void trans_iter(const float* __restrict__ partials,
                           const float* __restrict__ u_tan_in,
                           const float* __restrict__ rho,
                           const float* __restrict__ kv_w,
                           const float* __restrict__ mlp_w1,
                           const float* __restrict__ mlp_b1,
                           const float* __restrict__ mlp_w2,
                           const float* __restrict__ mlp_b2,
                           const float* __restrict__ q_u_w,
                           const float* __restrict__ q_g_w,
                           const float* __restrict__ q_g_b,
                           const float* __restrict__ ln_g,
                           const float* __restrict__ ln_b,
                           float* __restrict__ u_tan_out,
                           float* __restrict__ qvec_out,
                           float* __restrict__ mb,
                           float* __restrict__ out, int is_final) {
  const int b = blockIdx.x, tid = threadIdx.x;
  __shared__ __align__(16) float s_a[DH];
  __shared__ __align__(16) float s_b[DH];
  __shared__ __align__(16) float s_h[HID];
  __shared__ __align__(16) float s_rho[DG];
  __shared__ float s_red[2];

  float wv = combine_partials(partials, b, tid);
  s_a[tid] = wv;
  s_rho[tid] = rho[b * DG + tid];
  s_rho[tid + DH] = rho[b * DG + tid + DH];
  __syncthreads();
  float delta = dotN(kv_w + (size_t)tid * DH, s_a, DH / 4);
  s_b[tid] = delta;
  __syncthreads();
  float h0 = mlp_b1[tid] + dotN(mlp_w1 + (size_t)tid * DH, s_b, DH / 4);
  float h1 = mlp_b1[tid + DH] + dotN(mlp_w1 + (size_t)(tid + DH) * DH, s_b, DH / 4);
  s_h[tid] = 0.5f * h0 * (1.0f + erff(h0 * 0.70710678118654752f));
  s_h[tid + DH] = 0.5f * h1 * (1.0f + erff(h1 * 0.70710678118654752f));
  __syncthreads();
  float upd = mlp_b2[tid] + dotN(mlp_w2 + (size_t)tid * HID, s_h, HID / 4);
  float v = u_tan_in[b * DH + tid] + upd;
  // expmap0
  float n2 = blockSum128(v * v, s_red);
  float nc = fmaxf(sqrtf(n2), 1e-7f);
  float u = v * (tanhf(nc) / nc);
  if (is_final) {
    out[b * DH + tid] = u;
    return;
  }
  // logmap0
  float nu2 = blockSum128(u * u, s_red);
  float nuc = fmaxf(sqrtf(nu2), 1e-7f);
  float ut = u * (artanh_clip(nuc) / nuc);
  // LayerNorm
  float mu = blockSum128(ut, s_red) * (1.0f / DH);
  float d = ut - mu;
  float var = blockSum128(d * d, s_red) * (1.0f / DH);
  float y = d * rsqrtf(var + LN_EPS) * ln_g[tid] + ln_b[tid];
  u_tan_out[b * DH + tid] = y;
  s_a[tid] = y;
  __syncthreads();
  float q = q_g_b[tid] + dotN(q_u_w + (size_t)tid * DH, s_a, DH / 4) +
            dotN(q_g_w + (size_t)tid * DG, s_rho, DG / 4);
  s_b[tid] = q;
  __syncthreads();
  float qp = 0.f;
  for (int i = 0; i < DH; ++i) qp += kv_w[i * DH + tid] * s_b[i];
  qvec_out[b * DH + tid] = qp;
  float qn2 = blockSum128(qp * qp, s_red);
  if (tid == 0) mb[b] = SCALE * TAN_NORM_MAX * sqrtf(qn2);
}

// ---------- launch ----------

extern "C" void kernel_launch(void* const* d_in, const int* in_sizes, int n_in,
                              void* d_out, int out_size, void* d_ws, size_t ws_size,
                              hipStream_t stream) {
  const float* demo      = (const float*)d_in[0];
  const float* rho       = (const float*)d_in[1];
  const float* seed_g_w  = (const float*)d_in[2];
  const float* seed_g_b  = (const float*)d_in[3];
  const float* seed_d_w  = (const float*)d_in[4];
  const float* pool_wq_w = (const float*)d_in[5];
  const float* pool_wk_w = (const float*)d_in[6];
  const float* pool_wv_w = (const float*)d_in[7];
  const float* q_u_w     = (const float*)d_in[8];
  const float* q_g_w     = (const float*)d_in[9];
  const float* q_g_b     = (const float*)d_in[10];
  const float* kv_w      = (const float*)d_in[11];
  const float* mlp_w1    = (const float*)d_in[12];
  const float* mlp_b1    = (const float*)d_in[13];
  const float* mlp_w2    = (const float*)d_in[14];
  const float* mlp_b2    = (const float*)d_in[15];
  const float* ln_g      = (const float*)d_in[16];
  const float* ln_b      = (const float*)d_in[17];
  float* out = (float*)d_out;

  float* ws = (float*)d_ws;
  float* qvec  = ws;                 // B*DH
  float* qseed = ws + B * DH;        // B*DH
  float* utanA = ws + 2 * B * DH;    // B*DH
  float* utanB = ws + 3 * B * DH;    // B*DH
  float* mb    = ws + 4 * B * DH;    // B
  float* parts = ws + 4 * B * DH + B;               // B*SPLITS*(DH+2)
  float* tsbuf = parts + B * SPLITS * (DH + 2);     // B*N logmap scales

  setup_pool_query<<<B, DH, 0, stream>>>(rho, seed_g_w, seed_g_b, pool_wq_w,
                                         pool_wk_w, qseed, qvec, mb);
  attn_pass<0><<<B * SPLITS, 256, 0, stream>>>(demo, qvec, mb, parts, tsbuf);
  trans_pool<<<B, DH, 0, stream>>>(parts, qseed, rho, pool_wv_w, seed_d_w,
                                   q_u_w, q_g_w, q_g_b, kv_w, ln_g, ln_b,
                                   utanA, qvec, mb);
  attn_pass<1><<<B * SPLITS, 256, 0, stream>>>(demo, qvec, mb, parts, tsbuf);
  trans_iter<<<B, DH, 0, stream>>>(parts, utanA, rho, kv_w, mlp_w1, mlp_b1,
                                   mlp_w2, mlp_b2, q_u_w, q_g_w, q_g_b, ln_g,
                                   ln_b, utanB, qvec, mb, out, 0);
  attn_pass<1><<<B * SPLITS, 256, 0, stream>>>(demo, qvec, mb, parts, tsbuf);
  trans_iter<<<B, DH, 0, stream>>>(parts, utanB, rho, kv_w, mlp_w1, mlp_b1,
                                   mlp_w2, mlp_b2, q_u_w, q_g_w, q_g_b, ln_g,
                                   ln_b, utanB, qvec, mb, out, 1);
}

// Round 2
// 516.834 us; speedup vs baseline: 1.1911x; 1.1664x over previous
//
#include <hip/hip_runtime.h>
#include <cstddef>
#include <cstdint>

#define B 256
#define N 2048
#define DH 128
#define DG 256
#define HID 256
#define WAVES 8
#define TPB (WAVES * 64)     // 512 threads, 8 waves, 1 block per CU
#define RPI (WAVES * 8)      // 64 rows per block-iteration
#define KIT (N / RPI)        // 32 k-iterations per pass
#define SCALE 0.08838834764831845f
#define LN_EPS 1e-5f
#define TAN_NORM_MAX 6.2f    // artanh(1-1e-5)=6.103; safe upper bound

// ---------- helpers ----------

__device__ __forceinline__ float artanh_clip(float a) {
  a = fminf(a, 1.0f - 1e-5f);
  return 0.5f * __logf((1.0f + a) / (1.0f - a));
}

__device__ __forceinline__ float logmap_scale(float n2) {
  float nc = fmaxf(sqrtf(n2), 1e-7f);
  return artanh_clip(nc) / nc;
}

// allreduce-sum across each 16-lane DPP row using ROW_ROR (pure VALU)
__device__ __forceinline__ float row16_sum(float x) {
  x += __int_as_float(__builtin_amdgcn_update_dpp(0, __float_as_int(x), 0x128, 0xF, 0xF, true)); // ror:8
  x += __int_as_float(__builtin_amdgcn_update_dpp(0, __float_as_int(x), 0x124, 0xF, 0xF, true)); // ror:4
  x += __int_as_float(__builtin_amdgcn_update_dpp(0, __float_as_int(x), 0x122, 0xF, 0xF, true)); // ror:2
  x += __int_as_float(__builtin_amdgcn_update_dpp(0, __float_as_int(x), 0x121, 0xF, 0xF, true)); // ror:1
  return x;
}

__device__ __forceinline__ float wave_allsum(float v) {
#pragma unroll
  for (int m = 1; m < 64; m <<= 1) v += __shfl_xor(v, m);
  return v;
}

__device__ __forceinline__ float dot128(const float* __restrict__ wrow,
                                        const float* __restrict__ x) {
  const float4* a = (const float4*)wrow;
  const float4* v = (const float4*)x;
  float s = 0.f;
#pragma unroll
  for (int j = 0; j < 32; ++j) {
    float4 u = a[j], b = v[j];
    s += u.x * b.x + u.y * b.y + u.z * b.z + u.w * b.w;
  }
  return s;
}

__device__ __forceinline__ float dot256(const float* __restrict__ wrow,
                                        const float* __restrict__ x) {
  const float4* a = (const float4*)wrow;
  const float4* v = (const float4*)x;
  float s = 0.f;
#pragma unroll
  for (int j = 0; j < 64; ++j) {
    float4 u = a[j], b = v[j];
    s += u.x * b.x + u.y * b.y + u.z * b.z + u.w * b.w;
  }
  return s;
}

// ---------- fused per-batch refiner: one block = one batch, all passes ----------

__global__ __launch_bounds__(TPB, 2) void fused_refiner(
    const float* __restrict__ demo, const float* __restrict__ rho,
    const float* __restrict__ seed_g_w, const float* __restrict__ seed_g_b,
    const float* __restrict__ seed_d_w, const float* __restrict__ pool_wq_w,
    const float* __restrict__ pool_wk_w, const float* __restrict__ pool_wv_w,
    const float* __restrict__ q_u_w, const float* __restrict__ q_g_w,
    const float* __restrict__ q_g_b, const float* __restrict__ kv_w,
    const float* __restrict__ mlp_w1, const float* __restrict__ mlp_b1,
    const float* __restrict__ mlp_w2, const float* __restrict__ mlp_b2,
    const float* __restrict__ ln_g, const float* __restrict__ ln_b,
    float* __restrict__ out) {
  const int b = blockIdx.x;
  const int tid = threadIdx.x;
  const int w = tid >> 6;
  const int lane = tid & 63;
  const int g = lane >> 4;   // row within wave's 4-row group
  const int il = lane & 15;  // 16 lanes per row

  __shared__ __align__(16) float s_rho[DG];
  __shared__ __align__(16) float s_x[DH];
  __shared__ __align__(16) float s_y[DH];
  __shared__ __align__(16) float s_h[HID];
  __shared__ __align__(16) float s_ut[DH];
  __shared__ __align__(16) float s_qseed[DH];
  __shared__ __align__(16) float s_qvec[DH];
  __shared__ __align__(16) float s_fold[WAVES][DH];
  __shared__ float s_l[WAVES];
  __shared__ float s_red[WAVES];
  __shared__ float s_Mb;

  // block-wide sum; all threads must call (inactive contribute 0)
  auto bsumAll = [&](float v) -> float {
    v = wave_allsum(v);
    if (lane == 0) s_red[w] = v;
    __syncthreads();
    float r = s_red[0] + s_red[1] + s_red[2] + s_red[3] +
              s_red[4] + s_red[5] + s_red[6] + s_red[7];
    __syncthreads();
    return r;
  };

  // shared epilogue: expmap -> logmap -> LN -> q -> qvec -> Mb
  auto ln_query = [&](float v) {
    float n2 = bsumAll(tid < DH ? v * v : 0.f);
    float u = 0.f, ut = 0.f;
    if (tid < DH) {
      float nc = fmaxf(sqrtf(n2), 1e-7f);
      u = v * (tanhf(nc) / nc);
    }
    float nu2 = bsumAll(tid < DH ? u * u : 0.f);
    if (tid < DH) {
      float nuc = fmaxf(sqrtf(nu2), 1e-7f);
      ut = u * (artanh_clip(nuc) / nuc);
    }
    float mu = bsumAll(tid < DH ? ut : 0.f) * (1.0f / DH);
    float d = ut - mu;
    float var = bsumAll(tid < DH ? d * d : 0.f) * (1.0f / DH);
    if (tid < DH) {
      float y = d * rsqrtf(var + LN_EPS) * ln_g[tid] + ln_b[tid];
      s_ut[tid] = y;
      s_x[tid] = y;
    }
    __syncthreads();
    if (tid < DH) {
      s_y[tid] = q_g_b[tid] + dot128(q_u_w + (size_t)tid * DH, s_x) +
                 dot256(q_g_w + (size_t)tid * DG, s_rho);
    }
    __syncthreads();
    float qp = 0.f;
    if (tid < DH) {
#pragma unroll 8
      for (int i = 0; i < DH; ++i) qp += kv_w[i * DH + tid] * s_y[i];
      s_qvec[tid] = qp;
    }
    float qn2 = bsumAll(tid < DH ? qp * qp : 0.f);
    if (tid == 0) s_Mb = SCALE * TAN_NORM_MAX * sqrtf(qn2);
    __syncthreads();
  };

  // ---- setup: q_seed, pooled-attention query, Mb ----
  if (tid < DG) s_rho[tid] = rho[(size_t)b * DG + tid];
  __syncthreads();
  if (tid < DH) {
    float qs = seed_g_b[tid] + dot256(seed_g_w + (size_t)tid * DG, s_rho);
    s_qseed[tid] = qs;
    s_x[tid] = qs;
  }
  __syncthreads();
  if (tid < DH) s_y[tid] = dot128(pool_wq_w + (size_t)tid * DH, s_x);
  __syncthreads();
  float qp0 = 0.f;
  if (tid < DH) {
#pragma unroll 8
    for (int i = 0; i < DH; ++i) qp0 += pool_wk_w[i * DH + tid] * s_y[i];
    s_qvec[tid] = qp0;
  }
  float qn2 = bsumAll(tid < DH ? qp0 * qp0 : 0.f);
  if (tid == 0) s_Mb = SCALE * TAN_NORM_MAX * sqrtf(qn2);
  __syncthreads();

  const float* demo_b = demo + (size_t)b * N * DH;

  for (int pass = 0; pass < 3; ++pass) {
    // ---- attention pass over all N rows ----
    // Fixed-bound softmax: Mb >= max score (Cauchy-Schwarz), plain exp sums.
    // wave w, iter k covers rows k*64 + w*8 + {g, g+4}; 16 lanes per row,
    // 8 floats per lane (two float4 halves); 1-iter-ahead prefetch.
    const float4 qv0 = *(const float4*)&s_qvec[il * 4];
    const float4 qv1 = *(const float4*)&s_qvec[64 + il * 4];
    const float Mb = s_Mb;
    const float* p = demo_b + (size_t)(w * 8 + g) * DH + il * 4;

    float lsum = 0.f;
    float4 accL = make_float4(0.f, 0.f, 0.f, 0.f);
    float4 accH = make_float4(0.f, 0.f, 0.f, 0.f);

    float4 xa1 = *(const float4*)(p);
    float4 xa2 = *(const float4*)(p + 64);
    float4 xb1 = *(const float4*)(p + 4 * DH);
    float4 xb2 = *(const float4*)(p + 4 * DH + 64);

    for (int k = 0; k < KIT; ++k) {
      float4 ca1 = xa1, ca2 = xa2, cb1 = xb1, cb2 = xb2;
      if (k + 1 < KIT) {
        const float* pn = p + (size_t)(k + 1) * RPI * DH;
        xa1 = *(const float4*)(pn);
        xa2 = *(const float4*)(pn + 64);
        xb1 = *(const float4*)(pn + 4 * DH);
        xb2 = *(const float4*)(pn + 4 * DH + 64);
      }
      // group A (row k*64 + w*8 + g)
      {
        float dd = qv0.x * ca1.x + qv0.y * ca1.y + qv0.z * ca1.z + qv0.w * ca1.w +
                   qv1.x * ca2.x + qv1.y * ca2.y + qv1.z * ca2.z + qv1.w * ca2.w;
        float n2 = ca1.x * ca1.x + ca1.y * ca1.y + ca1.z * ca1.z + ca1.w * ca1.w +
                   ca2.x * ca2.x + ca2.y * ca2.y + ca2.z * ca2.z + ca2.w * ca2.w;
        dd = row16_sum(dd);
        n2 = row16_sum(n2);
        float tsv = logmap_scale(n2);
        float pw = __expf(dd * tsv * SCALE - Mb);
        lsum += pw;
        float c = pw * tsv;
        accL.x += c * ca1.x; accL.y += c * ca1.y; accL.z += c * ca1.z; accL.w += c * ca1.w;
        accH.x += c * ca2.x; accH.y += c * ca2.y; accH.z += c * ca2.z; accH.w += c * ca2.w;
      }
      // group B (row k*64 + w*8 + 4 + g)
      {
        float dd = qv0.x * cb1.x + qv0.y * cb1.y + qv0.z * cb1.z + qv0.w * cb1.w +
                   qv1.x * cb2.x + qv1.y * cb2.y + qv1.z * cb2.z + qv1.w * cb2.w;
        float n2 = cb1.x * cb1.x + cb1.y * cb1.y + cb1.z * cb1.z + cb1.w * cb1.w +
                   cb2.x * cb2.x + cb2.y * cb2.y + cb2.z * cb2.z + cb2.w * cb2.w;
        dd = row16_sum(dd);
        n2 = row16_sum(n2);
        float tsv = logmap_scale(n2);
        float pw = __expf(dd * tsv * SCALE - Mb);
        lsum += pw;
        float c = pw * tsv;
        accL.x += c * cb1.x; accL.y += c * cb1.y; accL.z += c * cb1.z; accL.w += c * cb1.w;
        accH.x += c * cb2.x; accH.y += c * cb2.y; accH.z += c * cb2.z; accH.w += c * cb2.w;
      }
    }

    // fold the 4 g-groups within each wave (same d-slice, disjoint rows)
    accL.x += __shfl_xor(accL.x, 16); accL.x += __shfl_xor(accL.x, 32);
    accL.y += __shfl_xor(accL.y, 16); accL.y += __shfl_xor(accL.y, 32);
    accL.z += __shfl_xor(accL.z, 16); accL.z += __shfl_xor(accL.z, 32);
    accL.w += __shfl_xor(accL.w, 16); accL.w += __shfl_xor(accL.w, 32);
    accH.x += __shfl_xor(accH.x, 16); accH.x += __shfl_xor(accH.x, 32);
    accH.y += __shfl_xor(accH.y, 16); accH.y += __shfl_xor(accH.y, 32);
    accH.z += __shfl_xor(accH.z, 16); accH.z += __shfl_xor(accH.z, 32);
    accH.w += __shfl_xor(accH.w, 16); accH.w += __shfl_xor(accH.w, 32);
    lsum += __shfl_xor(lsum, 16); lsum += __shfl_xor(lsum, 32);
    if (g == 0) {
      *(float4*)&s_fold[w][il * 4] = accL;
      *(float4*)&s_fold[w][64 + il * 4] = accH;
      if (il == 0) s_l[w] = lsum;
    }
    __syncthreads();

    if (tid < DH) {
      float a = 0.f;
#pragma unroll
      for (int j = 0; j < WAVES; ++j) a += s_fold[j][tid];
      float L = s_l[0] + s_l[1] + s_l[2] + s_l[3] +
                s_l[4] + s_l[5] + s_l[6] + s_l[7];
      s_x[tid] = a / L;  // weighted value sum (= sum p*t / sum p)
    }
    __syncthreads();

    // ---- transition ----
    if (pass == 0) {
      if (tid < DH) s_y[tid] = dot128(pool_wv_w + (size_t)tid * DH, s_x);
      __syncthreads();
      float v = 0.f;
      if (tid < DH) v = s_qseed[tid] + dot128(seed_d_w + (size_t)tid * DH, s_y);
      ln_query(v);
    } else {
      if (tid < DH) s_y[tid] = dot128(kv_w + (size_t)tid * DH, s_x);
      __syncthreads();
      if (tid < HID) {
        float h = mlp_b1[tid] + dot128(mlp_w1 + (size_t)tid * DH, s_y);
        s_h[tid] = 0.5f * h * (1.0f + erff(h * 0.70710678118654752f));
      }
      __syncthreads();
      float v = 0.f;
      if (tid < DH)
        v = s_ut[tid] + mlp_b2[tid] + dot256(mlp_w2 + (size_t)tid * HID, s_h);
      if (pass == 2) {
        float n2 = bsumAll(tid < DH ? v * v : 0.f);
        if (tid < DH) {
          float nc = fmaxf(sqrtf(n2), 1e-7f);
          out[(size_t)b * DH + tid] = v * (tanhf(nc) / nc);
        }
      } else {
        ln_query(v);
      }
    }
  }
}

// ---------- launch ----------

extern "C" void kernel_launch(void* const* d_in, const int* in_sizes, int n_in,
                              void* d_out, int out_size, void* d_ws, size_t ws_size,
                              hipStream_t stream) {
  const float* demo      = (const float*)d_in[0];
  const float* rho       = (const float*)d_in[1];
  const float* seed_g_w  = (const float*)d_in[2];
  const float* seed_g_b  = (const float*)d_in[3];
  const float* seed_d_w  = (const float*)d_in[4];
  const float* pool_wq_w = (const float*)d_in[5];
  const float* pool_wk_w = (const float*)d_in[6];
  const float* pool_wv_w = (const float*)d_in[7];
  const float* q_u_w     = (const float*)d_in[8];
  const float* q_g_w     = (const float*)d_in[9];
  const float* q_g_b     = (const float*)d_in[10];
  const float* kv_w      = (const float*)d_in[11];
  const float* mlp_w1    = (const float*)d_in[12];
  const float* mlp_b1    = (const float*)d_in[13];
  const float* mlp_w2    = (const float*)d_in[14];
  const float* mlp_b2    = (const float*)d_in[15];
  const float* ln_g      = (const float*)d_in[16];
  const float* ln_b      = (const float*)d_in[17];
  float* out = (float*)d_out;
  (void)d_ws; (void)ws_size; (void)in_sizes; (void)n_in; (void)out_size;

  fused_refiner<<<B, TPB, 0, stream>>>(demo, rho, seed_g_w, seed_g_b, seed_d_w,
                                       pool_wq_w, pool_wk_w, pool_wv_w, q_u_w,
                                       q_g_w, q_g_b, kv_w, mlp_w1, mlp_b1,
                                       mlp_w2, mlp_b2, ln_g, ln_b, out);
}